// Round 10
// baseline (33406.717 us; speedup 1.0000x reference)
//
#include <hip/hip_runtime.h>

// ShapeWeaverDecoder: 2-layer LSTM decoder, T=2048 steps, B=32, U=256.
// Round-10 = the islands design (r5-r8) finally realized as specified:
//  FIX 1 (the big one): r8's __launch_bounds__(512,2) still yielded VGPR=128
//    (hipcc occupancy heuristic) -> wA[128] partially spilled, ~40KB/block/step
//    scratch reloads = the entire 36ms plateau. Use the LLVM-native
//    __attribute__((amdgpu_waves_per_eu(2,2))): exactly 2 waves/EU -> 256-reg
//    budget -> wA[128]+~45 working regs fit with margin. VGPR_Count is the test.
//  FIX 2: r8's R2 LDS layout (row=col*4+khq, stride 66) was a 16-way bank
//    conflict (1.36e8). New layout row=khq*128+col, stride 68: consecutive
//    lanes = consecutive rows, b128 phase groups 17*l mod 8 all distinct ->
//    conflict-free.
// Everything else proven r5-r8 (absmax 0.0): 256 blocks x 512 thr, 1 block/CU,
// co-XCD islands via s_getreg(XCC_ID)+tickets, checksum records (torn/stale/
// poison fail validation; ring depth 2; no resets), dual fast(sc0/L2) +
// safe(sc0 sc1/MALL) rings with every-4th safe poll.

#define TSTEPS 2048
#define NB     32
#define NTHR   512
#define RECF   8

typedef float f4 __attribute__((ext_vector_type(4)));

// float offsets into dynamic LDS
constexpr int OFF_R2L  = 0;          // 512 rows x 68 = 34816 floats (R2 slice)
constexpr int OFF_H1   = 34816;      // 256 (16B-aligned)
constexpr int OFF_H2   = 35072;      // 256
constexpr int OFF_HIST = 35328;      // 64
constexpr int OFF_Z1   = 35392;      // 384 (stride-3 rows)
constexpr int OFF_Z2   = 35776;      // 1152 (stride-9 rows; prologue scratch stride-33)
constexpr int OFF_G1   = 36928;      // 128
constexpr int OFF_G2   = 37056;      // 128
constexpr int OFF_X    = 37184;      // 2
constexpr int OFF_ROLE = 37186;      // 1 int slot
constexpr int SMEM_BYTES = 37188 * 4;   // 148752 B -> exactly 1 block/CU

__device__ __forceinline__ float sigm(float x) { return 1.f / (1.f + expf(-x)); }

__device__ __forceinline__ float mk_chk(float a, float b, float c, float d, float t) {
  return __fadd_rn(__fadd_rn(__fadd_rn(__fadd_rn(a, b), c), d), t);
}
// fast: L1-bypass, L2-coherent (valid within an XCD)
__device__ __forceinline__ void load_rec_fast(const float* p, f4& a, float& chk) {
  asm volatile("global_load_dwordx4 %0, %2, off sc0\n\t"
               "global_load_dword %1, %2, off offset:16 sc0\n\t"
               "s_waitcnt vmcnt(0)"
               : "=&v"(a), "=&v"(chk) : "v"(p) : "memory");
}
// safe: MALL, device scope (proven r3-r9)
__device__ __forceinline__ void load_rec_safe(const float* p, f4& a, float& chk) {
  asm volatile("global_load_dwordx4 %0, %2, off sc0 sc1\n\t"
               "global_load_dword %1, %2, off offset:16 sc0 sc1\n\t"
               "s_waitcnt vmcnt(0)"
               : "=&v"(a), "=&v"(chk) : "v"(p) : "memory");
}
__device__ __forceinline__ void store_rec2(float* pf, float* ps, const f4& d, float chk) {
  asm volatile("global_store_dwordx4 %0, %2, off sc0\n\t"
               "global_store_dword %0, %3, off offset:16 sc0\n\t"
               "global_store_dwordx4 %1, %2, off sc0 sc1\n\t"
               "global_store_dword %1, %3, off offset:16 sc0 sc1"
               :: "v"(pf), "v"(ps), "v"(d), "v"(chk) : "memory");
}
__device__ __forceinline__ int recoff(int k, int b, int idx) {
  return (((k & 1) * NB + b) * 64 + idx) * RECF;
}

// Poll the 64 records of vector (k,b): lane l owns record l. Fast (XCD-L2) ring
// with safe (MALL) read every 4th iteration; brief backoff. Bounded.
__device__ __forceinline__ bool poll64(const float* ringF, const float* ringS,
                                       int k, int b, float tag, int lane,
                                       f4& d, bool ok) {
  if (!ok) return false;
  const int off = recoff(k, b, lane);
  const float* pf = ringF + off;
  const float* ps = ringS + off;
  bool v = false;
  int it = 0;
  while (!__all(v)) {
    if (!v) {
      f4 a; float cc;
      if ((it & 3) == 3) load_rec_safe(ps, a, cc);
      else               load_rec_fast(pf, a, cc);
      if (__float_as_uint(cc) == __float_as_uint(mk_chk(a.x, a.y, a.z, a.w, tag))) {
        d = a; v = true;
      }
    }
    if (++it > (1 << 15)) return false;
    if (it > 64) __builtin_amdgcn_s_sleep(8);
    else if (it > 16) __builtin_amdgcn_s_sleep(1);
  }
  return true;
}

__global__ __attribute__((amdgpu_waves_per_eu(2, 2))) __launch_bounds__(NTHR)
void swd_kernel(
    const float* __restrict__ ctx, const float* __restrict__ Wc, const float* __restrict__ bc,
    const float* __restrict__ K1, const float* __restrict__ R1, const float* __restrict__ b1,
    const float* __restrict__ K2, const float* __restrict__ R2, const float* __restrict__ b2,
    const float* __restrict__ Wo, const float* __restrict__ bo,
    float* __restrict__ dout, int* __restrict__ tick,
    float* __restrict__ ring1f, float* __restrict__ ring1s,
    float* __restrict__ ring2f, float* __restrict__ ring2s)
{
  extern __shared__ float sm[];
  float* r2l   = sm + OFF_R2L;
  float* h1buf = sm + OFF_H1;
  float* h2buf = sm + OFF_H2;
  float* hist  = sm + OFF_HIST;
  float* zbuf1 = sm + OFF_Z1;
  float* zbuf2 = sm + OFF_Z2;
  float* gbuf1 = sm + OFF_G1;
  float* gbuf2 = sm + OFF_G2;
  float* xbuf  = sm + OFF_X;

  const int t = threadIdx.x;

  // ---- runtime role assignment: co-XCD islands by construction (r7) ----
  int xcc;
  asm volatile("s_getreg_b32 %0, hwreg(HW_REG_XCC_ID)" : "=s"(xcc));
  xcc &= 7;
  if (t == 0) ((int*)sm)[OFF_ROLE] = atomicAdd(tick + xcc, 1);
  __syncthreads();
  const int ticket = ((int*)sm)[OFF_ROLE];
  const int b = (xcc * 4 + (ticket >> 3)) & 31;  // batch (island id)
  const int g = ticket & 7;                      // unit slice within island

  const int lane = t & 63;
  const bool w0  = (t < 64);
  const bool w7  = (t >= 448);
  const int col  = t & 127;          // local gate-col
  const int khq  = t >> 7;           // 0..3
  const int kh   = khq & 1;
  const int q    = col >> 5;         // gate (i,f,g,o)
  const int j    = col & 31;         // unit within slice
  const int kcol = q * 256 + 32 * g + j;   // keras gate-major column

  // ---- weights: wA in VGPRs (128/thread, budget 256), R2 into LDS ----
  const float* baseA = (t < 256) ? R1 : K2;
  float wA[128];
  #pragma unroll
  for (int m = 0; m < 128; ++m) wA[m] = baseA[(kh * 128 + m) * 1024 + kcol];
  {
    // row = khq*128 + col, stride 68: consecutive lanes -> consecutive rows,
    // b128 reads conflict-free (17*l mod 8 distinct).
    float* dst = r2l + (khq * 128 + col) * 68;
    #pragma unroll
    for (int m = 0; m < 64; ++m) dst[m] = R2[(khq * 64 + m) * 1024 + kcol];
  }

  float k1a = 0.f, k1b = 0.f, bb1 = 0.f, bb2 = 0.f;
  if (t < 128)      { k1a = K1[kcol]; k1b = K1[1024 + kcol]; bb1 = b1[kcol]; }
  else if (t < 256) { bb2 = b2[kcol]; }
  float wo0[4], wo1[4], bo0 = 0.f, bo1 = 0.f;
  if (w7) {
    #pragma unroll
    for (int m = 0; m < 4; ++m) {
      wo0[m] = Wo[(4 * lane + m) * 2];
      wo1[m] = Wo[(4 * lane + m) * 2 + 1];
    }
    bo0 = bo[0]; bo1 = bo[1];
  }

  // ---- prologue: h1[0] slice = relu(ctx @ Wc + bc), publish tag 0, stage ----
  {
    const int jj = t & 31, kc = t >> 5;      // 16 chunks of 32
    float p = 0.f;
    #pragma unroll
    for (int m = 0; m < 32; ++m)
      p = fmaf(ctx[b * 512 + kc * 32 + m], Wc[(kc * 32 + m) * 256 + 32 * g + jj], p);
    zbuf2[kc * 33 + jj] = p;
  }
  if (t == 0) { xbuf[0] = 0.5f; xbuf[1] = 0.5f; }
  if (t < 256) h2buf[t] = 0.f;
  __syncthreads();

  bool ok = true;
  float c1 = 0.f, c2 = 0.f, hn = 0.f;
  if (t < 32) {
    float sum = bc[32 * g + t];
    #pragma unroll
    for (int kc = 0; kc < 16; ++kc) sum += zbuf2[kc * 33 + t];
    hn = fmaxf(sum, 0.f);
  }
  if (w0) {
    const float h0  = __shfl(hn, (4 * lane + 0) & 31), h1v = __shfl(hn, (4 * lane + 1) & 31),
                h2v = __shfl(hn, (4 * lane + 2) & 31), h3v = __shfl(hn, (4 * lane + 3) & 31);
    if (lane < 8) {
      f4 dd; dd.x = h0; dd.y = h1v; dd.z = h2v; dd.w = h3v;
      const int off = recoff(0, b, g * 8 + lane);
      store_rec2(ring1f + off, ring1s + off, dd, mk_chk(h0, h1v, h2v, h3v, 0.f));
    }
  }
  if (w7) {
    f4 d;
    ok = poll64(ring1f, ring1s, 0, b, 0.f, lane, d, ok);
    *(f4*)(h1buf + 4 * lane) = d;
  }
  __syncthreads();

  // ==================== main loop (schedule proven r5-r8) ====================
  for (int s = 0; s < TSTEPS; ++s) {
    // P1: R1 half-dots on h1[s] (waves 0-3)  ||  P2: wave 7 polls h2[s] -> x
    if (t < 256) {
      float a0 = 0.f, a1 = 0.f, a2 = 0.f, a3 = 0.f;
      const f4* hp = (const f4*)(h1buf + kh * 128);
      #pragma unroll
      for (int m = 0; m < 32; ++m) {
        const f4 hv = hp[m];
        a0 = fmaf(wA[4 * m + 0], hv.x, a0);
        a1 = fmaf(wA[4 * m + 1], hv.y, a1);
        a2 = fmaf(wA[4 * m + 2], hv.z, a2);
        a3 = fmaf(wA[4 * m + 3], hv.w, a3);
      }
      zbuf1[col * 3 + kh] = (a0 + a1) + (a2 + a3);
    } else if (w7 && s > 0) {
      f4 gg;
      ok = poll64(ring2f, ring2s, s, b, (float)s, lane, gg, ok);
      *(f4*)(h2buf + 4 * lane) = gg;                 // lane l holds units 4l..4l+3
      float po0 = gg.x * wo0[0] + gg.y * wo0[1] + gg.z * wo0[2] + gg.w * wo0[3];
      float po1 = gg.x * wo1[0] + gg.y * wo1[1] + gg.z * wo1[2] + gg.w * wo1[3];
      #pragma unroll
      for (int dd = 1; dd < 64; dd <<= 1) { po0 += __shfl_xor(po0, dd); po1 += __shfl_xor(po1, dd); }
      const float x0 = sigm(po0 + bo0), x1 = sigm(po1 + bo1);
      if (lane == 0) {
        xbuf[0] = x0; xbuf[1] = x1;
        if (g == 0) { hist[((s - 1) & 31) * 2] = x0; hist[((s - 1) & 31) * 2 + 1] = x1; }
      }
    }
    __syncthreads();  // B1

    // P3: z1 finalize (t<128, critical), then R2 quarter-dots (all threads, LDS)
    if (t < 128) {
      const float z = (zbuf1[3 * t] + zbuf1[3 * t + 1]) + xbuf[0] * k1a + xbuf[1] * k1b + bb1;
      gbuf1[t] = (q == 2) ? tanhf(z) : sigm(z);
    }
    {
      float a0 = 0.f, a1 = 0.f, a2 = 0.f, a3 = 0.f;
      const f4* hp = (const f4*)(h2buf + khq * 64);
      const float* wp = r2l + (khq * 128 + col) * 68;
      #pragma unroll
      for (int m = 0; m < 16; ++m) {
        const f4 hv = hp[m];
        const f4 wv = *(const f4*)(wp + 4 * m);
        a0 = fmaf(wv.x, hv.x, a0);
        a1 = fmaf(wv.y, hv.y, a1);
        a2 = fmaf(wv.z, hv.z, a2);
        a3 = fmaf(wv.w, hv.w, a3);
      }
      zbuf2[col * 9 + khq] = (a0 + a1) + (a2 + a3);
    }
    if (w7 && g == 0 && s >= 32 && (s & 31) == 0 && lane < 16) {   // batched dout flush
      const f4 v = *(const f4*)(hist + 4 * lane);
      *(f4*)(dout + (b * TSTEPS + (s - 32)) * 2 + 4 * lane) = v;
    }
    __syncthreads();  // C

    // P4: h1 update + publish (wave 0)  ||  P5: wave 7 polls h1[s+1]
    if (t < 32) {
      const float gi = gbuf1[t], gf = gbuf1[32 + t], gG = gbuf1[64 + t], gO = gbuf1[96 + t];
      const float cn = gf * c1 + gi * gG;
      c1 = cn;
      hn = gO * tanhf(cn);
    }
    if (w0) {
      const float h0  = __shfl(hn, (4 * lane + 0) & 31), h1v = __shfl(hn, (4 * lane + 1) & 31),
                  h2v = __shfl(hn, (4 * lane + 2) & 31), h3v = __shfl(hn, (4 * lane + 3) & 31);
      if (lane < 8) {
        f4 dd; dd.x = h0; dd.y = h1v; dd.z = h2v; dd.w = h3v;
        const int off = recoff(s + 1, b, g * 8 + lane);
        store_rec2(ring1f + off, ring1s + off, dd, mk_chk(h0, h1v, h2v, h3v, (float)(s + 1)));
      }
    }
    if (w7) {
      f4 d;
      ok = poll64(ring1f, ring1s, s + 1, b, (float)(s + 1), lane, d, ok);
      *(f4*)(h1buf + 4 * lane) = d;
    }
    __syncthreads();  // D

    // P6: K2 half-dots on h1[s+1] (waves 4-7)
    if (t >= 256) {
      float a0 = 0.f, a1 = 0.f, a2 = 0.f, a3 = 0.f;
      const f4* hp = (const f4*)(h1buf + kh * 128);
      #pragma unroll
      for (int m = 0; m < 32; ++m) {
        const f4 hv = hp[m];
        a0 = fmaf(wA[4 * m + 0], hv.x, a0);
        a1 = fmaf(wA[4 * m + 1], hv.y, a1);
        a2 = fmaf(wA[4 * m + 2], hv.z, a2);
        a3 = fmaf(wA[4 * m + 3], hv.w, a3);
      }
      zbuf2[col * 9 + 4 + kh] = (a0 + a1) + (a2 + a3);
    }
    __syncthreads();  // E

    // P7: z2 finalize (waves 2-3)
    if (t >= 128 && t < 256) {
      const int c = t - 128;
      const float z = ((zbuf2[c * 9 + 0] + zbuf2[c * 9 + 1]) + (zbuf2[c * 9 + 2] + zbuf2[c * 9 + 3]))
                    + (zbuf2[c * 9 + 4] + zbuf2[c * 9 + 5]) + bb2;
      gbuf2[c] = (q == 2) ? tanhf(z) : sigm(z);
    }
    __syncthreads();  // F

    // P8: h2 update + publish (wave 0, lanes 32-63)
    if (t >= 32 && t < 64) {
      const int jj = t - 32;
      const float gi = gbuf2[jj], gf = gbuf2[32 + jj], gG = gbuf2[64 + jj], gO = gbuf2[96 + jj];
      const float cn = gf * c2 + gi * gG;
      c2 = cn;
      hn = gO * tanhf(cn);
    }
    if (w0) {
      const float h0  = __shfl(hn, 32 + ((4 * lane + 0) & 31)), h1v = __shfl(hn, 32 + ((4 * lane + 1) & 31)),
                  h2v = __shfl(hn, 32 + ((4 * lane + 2) & 31)), h3v = __shfl(hn, 32 + ((4 * lane + 3) & 31));
      if (lane >= 32 && lane < 40) {
        f4 dd; dd.x = h0; dd.y = h1v; dd.z = h2v; dd.w = h3v;
        const int off = recoff(s + 1, b, g * 8 + (lane - 32));
        store_rec2(ring2f + off, ring2s + off, dd, mk_chk(h0, h1v, h2v, h3v, (float)(s + 1)));
      }
    }
    // no barrier: exchange is via global memory; next step's B1 covers LDS ordering
  }

  // ---- epilogue: out[T-1] from h2[T] (island's g==0 block), final flush ----
  if (g == 0 && w7) {
    f4 gg;
    ok = poll64(ring2f, ring2s, TSTEPS, b, (float)TSTEPS, lane, gg, ok);
    float po0 = gg.x * wo0[0] + gg.y * wo0[1] + gg.z * wo0[2] + gg.w * wo0[3];
    float po1 = gg.x * wo1[0] + gg.y * wo1[1] + gg.z * wo1[2] + gg.w * wo1[3];
    #pragma unroll
    for (int dd = 1; dd < 64; dd <<= 1) { po0 += __shfl_xor(po0, dd); po1 += __shfl_xor(po1, dd); }
    if (lane == 0) { hist[62] = sigm(po0 + bo0); hist[63] = sigm(po1 + bo1); }
    if (lane < 16) {
      const f4 v = *(const f4*)(hist + 4 * lane);
      *(f4*)(dout + (b * TSTEPS + TSTEPS - 32) * 2 + 4 * lane) = v;
    }
  }
  (void)ok;
}

extern "C" void kernel_launch(void* const* d_in, const int* in_sizes, int n_in,
                              void* d_out, int out_size, void* d_ws, size_t ws_size,
                              hipStream_t stream) {
  (void)in_sizes; (void)n_in; (void)out_size; (void)ws_size;
  const float* ctx = (const float*)d_in[0];
  const float* Wc  = (const float*)d_in[1];
  const float* bc  = (const float*)d_in[2];
  const float* K1  = (const float*)d_in[3];
  const float* R1  = (const float*)d_in[4];
  const float* b1  = (const float*)d_in[5];
  const float* K2  = (const float*)d_in[6];
  const float* R2  = (const float*)d_in[7];
  const float* b2  = (const float*)d_in[8];
  const float* Wo  = (const float*)d_in[9];
  const float* bo  = (const float*)d_in[10];

  const int RING = 2 * NB * 64 * RECF;           // 32768 floats = 128 KiB
  int*   tick   = (int*)d_ws;                    // [8] per-XCD ticket counters
  float* base   = (float*)((char*)d_ws + 256);
  float* ring1f = base;                          // fast (XCD-L2) rings
  float* ring2f = ring1f + RING;
  float* ring1s = ring2f + RING;                 // safe (MALL) rings
  float* ring2s = ring1s + RING;                 // total 512 KiB + 256 B
  // Rings need no reset (self-validating records). Tickets must start at 0.
  hipMemsetAsync(d_ws, 0, 8 * sizeof(int), stream);

  hipFuncSetAttribute((const void*)swd_kernel,
                      hipFuncAttributeMaxDynamicSharedMemorySize, SMEM_BYTES);
  swd_kernel<<<dim3(256), dim3(NTHR), SMEM_BYTES, stream>>>(
      ctx, Wc, bc, K1, R1, b1, K2, R2, b2, Wo, bo,
      (float*)d_out, tick, ring1f, ring1s, ring2f, ring2s);
}